// Round 6
// baseline (308.181 us; speedup 1.0000x reference)
//
#include <hip/hip_runtime.h>
#include <hip/hip_bf16.h>

typedef unsigned short u16;
typedef unsigned int u32;
typedef __attribute__((ext_vector_type(8))) short short8x;   // 8 bf16 (4 VGPR)
typedef __attribute__((ext_vector_type(4))) float f32x4;

__device__ __forceinline__ u16 bf16u(float x) {
    __hip_bfloat16 h = __float2bfloat16(x);
    return *reinterpret_cast<u16*>(&h);
}

__device__ __forceinline__ void gload_lds16(const void* g, void* l) {
    __builtin_amdgcn_global_load_lds(
        (const __attribute__((address_space(1))) u32*)g,
        (__attribute__((address_space(3))) u32*)l, 16, 0, 0);
}

// m=64, n=1024, W=H=512
#define M_  64
#define N_  1024
#define W_  512
#define SP_ROW 163840   // packed S' row length per i: 10 tiles * 16384

// ---------------------------------------------------------------------------
// K1: normalize psi rows (axis=2) and write transposed bf16 psiT[i][w][n].
// Single-pass: each thread owns a quarter-row (32 float4 = 128 VGPR) across
// the norm reduction, so psi is fetched from HBM exactly once.
// grid (16, 64): 64 n-rows of one i per block. block=256.
// ---------------------------------------------------------------------------
__global__ __launch_bounds__(256) void psinorm_t(const float* __restrict__ psi,
                                                 u16* __restrict__ psiT) {
    const int i  = blockIdx.y;
    const int nb = blockIdx.x;          // 64-row chunk
    const int t  = threadIdx.x;
    const float* base = psi + ((size_t)i * N_ + (size_t)nb * 64) * W_;

    __shared__ float red[256];
    __shared__ float invs[64];
    __shared__ u32   tile[64][257];     // = u16[64][514]: bank-stride-1 transpose

    const int r = t >> 2, p = t & 3;    // row within chunk / quarter
    const float4* rb = (const float4*)(base + r * W_ + p * 4);

    // phase A: load quarter-row into registers, sum of squares
    float4 v[32];
    float s = 0.f;
#pragma unroll
    for (int k = 0; k < 32; ++k) {
        v[k] = rb[k * 4];               // float w = p*4 + 16k .. +3
        s += v[k].x * v[k].x + v[k].y * v[k].y + v[k].z * v[k].z + v[k].w * v[k].w;
    }
    red[t] = s;
    __syncthreads();
    if (t < 64) {
        float ss = red[4 * t] + red[4 * t + 1] + red[4 * t + 2] + red[4 * t + 3];
        invs[t] = 1.0f / fmaxf(sqrtf(ss), 1e-12f);
    }
    __syncthreads();

    // phase B: rescale from registers, pack bf16 pairs into LDS
    {
        const float inv = invs[r];
#pragma unroll
        for (int k = 0; k < 32; ++k) {
            u32 p0 = (u32)bf16u(v[k].x * inv) | ((u32)bf16u(v[k].y * inv) << 16);
            u32 p1 = (u32)bf16u(v[k].z * inv) | ((u32)bf16u(v[k].w * inv) << 16);
            int wh = p * 2 + k * 8;     // (p*4 + 16k) >> 1
            tile[r][wh]     = p0;
            tile[r][wh + 1] = p1;
        }
    }
    __syncthreads();

    // phase C: transposed write: psiT[i][w][nb*64 + lane]
    // LDS read bank = (lane*257 + w/2) % 32 -> stride 1 in lane: conflict-free.
    {
        const u16* t16 = (const u16*)&tile[0][0];
        int wv = t >> 6, lane = t & 63;
        size_t obase = (size_t)i * W_ * N_ + (size_t)nb * 64 + lane;
#pragma unroll 4
        for (int it = 0; it < 128; ++it) {
            int w = it * 4 + wv;
            psiT[obase + (size_t)w * N_] = t16[lane * 514 + w];
        }
    }
}

// ---------------------------------------------------------------------------
// K2: batched SYRK  S_i = psiT_i * psiT_i^T, upper-triangle 128x128 tiles only.
// psiT_i is 512(w) x 1024(n) bf16, k(=n)-contiguous: serves BOTH operands.
// grid 640 flat, XCD-swizzled: x=L&7, q=L>>3, i=x*8+q/10, bt=q%10 (bijective)
// so all 10 tiles of an i share one XCD's L2 (5x panel reuse).
// block = 256 (4 waves, 2x2), BK = 64, 16 K-iters. XOR-swizzled LDS (m173/m201).
// Output packed: Sp[i][tile][wl*128+vl] scaled by sqrt(2) on off-diag tiles
// so that b[i][j] = <Sp_i, Sp_j> exactly reproduces the full Frobenius product.
// ---------------------------------------------------------------------------
__global__ __launch_bounds__(256) void syrk_bf16(const u16* __restrict__ psiT,
                                                 u16* __restrict__ Sp) {
    const int L = blockIdx.x;
    const int q = L >> 3;
    const int i  = (L & 7) * 8 + q / 10;
    const int bt = q % 10;
    int tr, tc;
    if      (bt < 4) { tr = 0; tc = bt;     }
    else if (bt < 7) { tr = 1; tc = bt - 3; }
    else if (bt < 9) { tr = 2; tc = bt - 5; }
    else             { tr = 3; tc = 3;      }
    const int t = threadIdx.x;

    const u16* Abase = psiT + (size_t)i * W_ * N_ + (size_t)tr * 128 * N_;
    const u16* Bbase = psiT + (size_t)i * W_ * N_ + (size_t)tc * 128 * N_;

    __shared__ u16 ldsA[128][64];   // 16 KB, [row][k], XOR-swizzled 16B chunks
    __shared__ u16 ldsB[128][64];

    const int lane = t & 63, wv = t >> 6;
    const int wr = wv >> 1, wc = wv & 1;
    const int lrow = lane & 15, lk8 = lane >> 4;   // frag row / k-chunk

    f32x4 acc[4][4];
#pragma unroll
    for (int a = 0; a < 4; ++a)
#pragma unroll
        for (int b = 0; b < 4; ++b) acc[a][b] = (f32x4){0.f, 0.f, 0.f, 0.f};

    for (int kt = 0; kt < 16; ++kt) {
        const int k0 = kt * 64;
        __syncthreads();
        // stage both tiles: 1024 16B chunks each, 4 rounds of 256 lanes.
        // LDS dest linear in c (wave-uniform base + lane*16): gload_lds-safe.
        // Swizzle applied on the GLOBAL source chunk (pre-swizzled, m173):
        // LDS chunk cch holds global chunk cch^(row&7)  (involution).
#pragma unroll
        for (int r = 0; r < 4; ++r) {
            int c = r * 256 + t;
            int row = c >> 3, cch = c & 7;
            int scch = cch ^ (row & 7);
            gload_lds16(Abase + (size_t)row * N_ + k0 + scch * 8, &ldsA[row][cch * 8]);
            gload_lds16(Bbase + (size_t)row * N_ + k0 + scch * 8, &ldsB[row][cch * 8]);
        }
        __syncthreads();

#pragma unroll
        for (int ks = 0; ks < 2; ++ks) {
            short8x af[4], bf[4];
#pragma unroll
            for (int mf = 0; mf < 4; ++mf) {
                int row = wr * 64 + mf * 16 + lrow;
                int ch = (ks * 4 + lk8) ^ (row & 7);
                af[mf] = *(const short8x*)&ldsA[row][ch * 8];
            }
#pragma unroll
            for (int nf = 0; nf < 4; ++nf) {
                int row = wc * 64 + nf * 16 + lrow;
                int ch = (ks * 4 + lk8) ^ (row & 7);
                bf[nf] = *(const short8x*)&ldsB[row][ch * 8];
            }
#pragma unroll
            for (int mf = 0; mf < 4; ++mf)
#pragma unroll
                for (int nf = 0; nf < 4; ++nf)
                    acc[mf][nf] = __builtin_amdgcn_mfma_f32_16x16x32_bf16(
                        af[mf], bf[nf], acc[mf][nf], 0, 0, 0);
        }
    }

    // epilogue: C/D layout col=lane&15, row=(lane>>4)*4+reg (m89-verified).
    // Wave-uniform sqrt(2) scale on off-diagonal-block tiles.
    const float sc = (tr == tc) ? 1.0f : 1.41421356237f;
    size_t Sbase = (size_t)i * SP_ROW + (size_t)bt * 16384;
#pragma unroll
    for (int mf = 0; mf < 4; ++mf)
#pragma unroll
        for (int nf = 0; nf < 4; ++nf)
#pragma unroll
            for (int reg = 0; reg < 4; ++reg) {
                int wl = wr * 64 + mf * 16 + lk8 * 4 + reg;
                int vl = wc * 64 + nf * 16 + lrow;
                Sp[Sbase + (size_t)wl * 128 + vl] = bf16u(acc[mf][nf][reg] * sc);
            }
}

// ---------------------------------------------------------------------------
// K3: b_partial = Sp * Sp^T over a 256-elem K-chunk (Sp: 64 x 163840 bf16).
// No LDS: per-block chunk is 32 KB, L1/L2-resident (4x reuse).
// grid 640, block 256 (4 waves 2x2, each 32x32 of the 64x64 output).
// ---------------------------------------------------------------------------
__global__ __launch_bounds__(256) void bgemm(const u16* __restrict__ Sp,
                                             float* __restrict__ bp) {
    const int t = threadIdx.x;
    const int lane = t & 63, wv = t >> 6;
    const int wr = wv >> 1, wc = wv & 1;
    const int lrow = lane & 15, lk8 = lane >> 4;
    const size_t kc0 = (size_t)blockIdx.x * 256;

    f32x4 acc[2][2];
#pragma unroll
    for (int a = 0; a < 2; ++a)
#pragma unroll
        for (int b = 0; b < 2; ++b) acc[a][b] = (f32x4){0.f, 0.f, 0.f, 0.f};

#pragma unroll
    for (int ks = 0; ks < 8; ++ks) {
        short8x af[2], bf[2];
#pragma unroll
        for (int mf = 0; mf < 2; ++mf) {
            int row = wr * 32 + mf * 16 + lrow;
            af[mf] = *(const short8x*)(Sp + (size_t)row * SP_ROW + kc0 + (ks * 4 + lk8) * 8);
        }
#pragma unroll
        for (int nf = 0; nf < 2; ++nf) {
            int row = wc * 32 + nf * 16 + lrow;
            bf[nf] = *(const short8x*)(Sp + (size_t)row * SP_ROW + kc0 + (ks * 4 + lk8) * 8);
        }
#pragma unroll
        for (int mf = 0; mf < 2; ++mf)
#pragma unroll
            for (int nf = 0; nf < 2; ++nf)
                acc[mf][nf] = __builtin_amdgcn_mfma_f32_16x16x32_bf16(
                    af[mf], bf[nf], acc[mf][nf], 0, 0, 0);
    }

    float* out = bp + (size_t)blockIdx.x * 4096;
#pragma unroll
    for (int mf = 0; mf < 2; ++mf)
#pragma unroll
        for (int nf = 0; nf < 2; ++nf)
#pragma unroll
            for (int reg = 0; reg < 4; ++reg) {
                int ir = wr * 32 + mf * 16 + lk8 * 4 + reg;
                int jc = wc * 32 + nf * 16 + lrow;
                out[ir * 64 + jc] = acc[mf][nf][reg];
            }
}

// ---------------------------------------------------------------------------
// K4: per block i: reduce b-row i over 640 partials; recompute phi norms/dots;
// parts[i] = sum_j (phi_i.phi_j)^2/(ni^2 nj^2) * b[i,j].  grid 64, block 256.
// ---------------------------------------------------------------------------
__global__ __launch_bounds__(256) void bfinal(const float* __restrict__ bp,
                                              const float* __restrict__ phi,
                                              float* __restrict__ parts) {
    const int i = blockIdx.x, t = threadIdx.x;
    const int lane = t & 63, wv = t >> 6;

    __shared__ float red[256];
    __shared__ float brow[64];
    __shared__ float pi[512];
    __shared__ float dj[64], nsq[64];

    // b-row reduction: 4 slices over partials
    {
        float s = 0.f;
        for (int p = wv; p < 640; p += 4) s += bp[(size_t)p * 4096 + i * 64 + lane];
        red[t] = s;
    }
    pi[t] = phi[i * 512 + t];
    pi[t + 256] = phi[i * 512 + 256 + t];
    __syncthreads();
    if (t < 64) brow[t] = red[t] + red[64 + t] + red[128 + t] + red[192 + t];

    // phi dots + norms (wave wv handles j = wv + 4*jj)
    for (int jj = 0; jj < 16; ++jj) {
        int j = wv + jj * 4;
        const float* pj = phi + j * 512;
        float d = 0.f, nn = 0.f;
#pragma unroll
        for (int e = 0; e < 8; ++e) {
            float x = pj[lane + e * 64];
            d += pi[lane + e * 64] * x;
            nn += x * x;
        }
#pragma unroll
        for (int o = 32; o; o >>= 1) {
            d += __shfl_xor(d, o);
            nn += __shfl_xor(nn, o);
        }
        if (lane == 0) { dj[j] = d; nsq[j] = nn; }
    }
    __syncthreads();
    if (t < 64) {
        float ni = fmaxf(sqrtf(nsq[i]), 1e-12f);
        float nj = fmaxf(sqrtf(nsq[t]), 1e-12f);
        float g = dj[t] / (ni * nj);
        float val = g * g * brow[t];
#pragma unroll
        for (int o = 32; o; o >>= 1) val += __shfl_down(val, o);
        if (t == 0) parts[i] = val;
    }
}

// K5: out = sum(parts) - m*n. grid 1, block 64.
__global__ void fsum(const float* __restrict__ parts, float* __restrict__ out) {
    const int t = threadIdx.x;
    float s = parts[t];
#pragma unroll
    for (int o = 32; o; o >>= 1) s += __shfl_down(s, o);
    if (t == 0) out[0] = s - 65536.0f;
}

// Fallback marker if workspace is too small (visible-wrong, not OOB-crash).
__global__ void wsfail(float* __restrict__ out) {
    if (threadIdx.x == 0) out[0] = 1.0e30f;
}

extern "C" void kernel_launch(void* const* d_in, const int* in_sizes, int n_in,
                              void* d_out, int out_size, void* d_ws, size_t ws_size,
                              hipStream_t stream) {
    const float* phi = (const float*)d_in[0];
    const float* psi = (const float*)d_in[1];
    float* out = (float*)d_out;
    char* ws = (char*)d_ws;

    // workspace layout (bytes), regions ALIASED by lifetime:
    //   [0 .. 64MB)      psiT  bf16 [64][512][1024]   (live: K1 -> K2)
    //   [0 .. 10.5MB)    bp    f32  [640][4096]       (live: K3 -> K4; aliases dead psiT)
    //   [64MB .. 84MB)   Sp    bf16 [64][163840]      (live: K2 -> K3)
    //   [84MB .. +256B)  parts f32  [64]              (live: K4 -> K5)
    const size_t NEEDED = 67108864ull + 20971520ull + 256ull;   // 88,080,640
    if (ws_size < NEEDED) {                 // deterministic across calls
        wsfail<<<1, 64, 0, stream>>>(out);
        return;
    }
    u16*   psiT  = (u16*)(ws);
    float* bp    = (float*)(ws);
    u16*   Sp    = (u16*)(ws + 67108864);
    float* parts = (float*)(ws + 88080384);

    psinorm_t<<<dim3(16, 64), 256, 0, stream>>>(psi, psiT);
    syrk_bf16<<<640,          256, 0, stream>>>(psiT, Sp);
    bgemm    <<<640,          256, 0, stream>>>(Sp, bp);
    bfinal   <<<64,           256, 0, stream>>>(bp, phi, parts);
    fsum     <<<1,            64,  0, stream>>>(parts, out);
}